// Round 5
// baseline (381.734 us; speedup 1.0000x reference)
//
#include <hip/hip_runtime.h>
#include <hip/hip_bf16.h>

// Problem constants (fixed by setup_inputs)
#define DIMC 1024
#define HC   16
#define DC   64
#define BC   4
#define SC   4096
#define ANC  512          // num_anchor_tokens
#define QNC  3584         // S - A
#define GK   1024         // K-dim of every GEMM (= DIMC)
// Q pre-scale: 1/sqrt(64) * log2(e)  (softmax exp done as exp2f; any Q scale
// just moves where bf16 rounding happens — relative error unchanged)
#define QSCALE (0.125f * 1.44269504088896f)

typedef __attribute__((ext_vector_type(4))) float f32x4;
typedef __attribute__((ext_vector_type(8))) short s16x8;
typedef __attribute__((ext_vector_type(4))) short s16x4;

__device__ inline short f2bf(float f) {
    unsigned u = __builtin_bit_cast(unsigned, f);
    u += 0x7fff + ((u >> 16) & 1);          // RNE
    return (short)(u >> 16);
}
__device__ inline unsigned cvtpk(float lo, float hi) {   // dst = {lo16: bf(lo), hi16: bf(hi)}
    unsigned d;
    asm("v_cvt_pk_bf16_f32 %0, %1, %2" : "=v"(d) : "v"(lo), "v"(hi));
    return d;
}

// async 16B global -> LDS (linear dest: wave-uniform base + lane*16)
#define GLOAD16(gp, lp) __builtin_amdgcn_global_load_lds( \
    (const __attribute__((address_space(1))) void*)(gp),  \
    (__attribute__((address_space(3))) void*)(lp), 16, 0, 0)

// ---------------- pre-pass: cast x to bf16 ----------------
__global__ __launch_bounds__(256) void cast_f32_bf16(
    const float* __restrict__ in, short* __restrict__ out, int n4)
{
    int i = blockIdx.x * blockDim.x + threadIdx.x;
    const int stride = gridDim.x * blockDim.x;
    for (; i < n4; i += stride) {
        float4 v = ((const float4*)in)[i];
        s16x4 o = { f2bf(v.x), f2bf(v.y), f2bf(v.z), f2bf(v.w) };
        ((s16x4*)out)[i] = o;
    }
}

// ---------------- pre-pass: W (K x N fp32) -> Wt (N x K bf16) ----------------
__global__ __launch_bounds__(256) void transpose_cast(
    const float* __restrict__ W, short* __restrict__ Wt, int K, int N)
{
    __shared__ float t[32][33];
    const int tx = threadIdx.x & 31, ty = threadIdx.x >> 5;  // 32 x 8
    const int nt = blockIdx.x * 32, kt = blockIdx.y * 32;
    #pragma unroll
    for (int j = 0; j < 4; ++j)
        t[ty + 8 * j][tx] = W[(size_t)(kt + ty + 8 * j) * N + nt + tx];
    __syncthreads();
    #pragma unroll
    for (int j = 0; j < 4; ++j)
        Wt[(size_t)(nt + ty + 8 * j) * K + kt + tx] = f2bf(t[tx][ty + 8 * j]);
}

// ---------------- bf16 MFMA GEMM (m97 structure: 128x128 tile, BK=32) ----------------
// mode: 0 = qkv scatter (bf16 Q/K/Vt), 1 = q scatter (bf16 Q), 2 = fp32 plain.
__global__ __launch_bounds__(256) void gemm_bf16(
    const short* __restrict__ Abase, const short* __restrict__ Bt,
    const float* __restrict__ bias,
    float* __restrict__ outF, short* __restrict__ outQ,
    short* __restrict__ outK, short* __restrict__ outVt,
    int rowsPerB, int rowOff, int mode)
{
    __shared__ __align__(16) short Als[128 * 32];   // [row][k] linear, 8 KB
    __shared__ __align__(16) short Bls[128 * 32];   // [n][k]  linear, 8 KB

    const int tid = threadIdx.x;
    const int wave = tid >> 6, lane = tid & 63;
    const int q = lane & 15, g = lane >> 4;
    const int wm = wave >> 1, wn = wave & 1;

    const int bm = blockIdx.y * 128, bn = blockIdx.x * 128;
    const int bb = bm / rowsPerB;            // batch index (tiles never straddle)
    const int blocal = bm % rowsPerB;
    const char* Arow0 = (const char*)(Abase + ((size_t)bb * SC + rowOff + blocal) * GK);
    const char* Brow0 = (const char*)(Bt + (size_t)bn * GK);

    const int ca0 = wave * 64 + lane;        // 0..255   (rows 0..63)
    const int ca1 = (4 + wave) * 64 + lane;  // 256..511 (rows 64..127)
    const int a0r = (ca0 >> 2) * (GK * 2), a0c = (ca0 & 3) * 16;
    const int a1r = (ca1 >> 2) * (GK * 2), a1c = (ca1 & 3) * 16;

    f32x4 acc[4][4];
    #pragma unroll
    for (int i = 0; i < 4; ++i)
        #pragma unroll
        for (int j = 0; j < 4; ++j) acc[i][j] = (f32x4){0.f, 0.f, 0.f, 0.f};

    for (int k0 = 0; k0 < GK; k0 += 32) {
        const int kb = k0 * 2;               // byte offset within a row
        GLOAD16(Arow0 + a0r + kb + a0c, (char*)Als + ca0 * 16);
        GLOAD16(Arow0 + a1r + kb + a1c, (char*)Als + ca1 * 16);
        GLOAD16(Brow0 + a0r + kb + a0c, (char*)Bls + ca0 * 16);
        GLOAD16(Brow0 + a1r + kb + a1c, (char*)Bls + ca1 * 16);
        __syncthreads();

        s16x8 aF[4], bF[4];
        #pragma unroll
        for (int mi = 0; mi < 4; ++mi)
            aF[mi] = *(const s16x8*)((const char*)Als + (wm * 64 + mi * 16 + q) * 64 + g * 16);
        #pragma unroll
        for (int ni = 0; ni < 4; ++ni)
            bF[ni] = *(const s16x8*)((const char*)Bls + (wn * 64 + ni * 16 + q) * 64 + g * 16);
        #pragma unroll
        for (int mi = 0; mi < 4; ++mi)
            #pragma unroll
            for (int ni = 0; ni < 4; ++ni)
                acc[mi][ni] = __builtin_amdgcn_mfma_f32_16x16x32_bf16(
                    aF[mi], bF[ni], acc[mi][ni], 0, 0, 0);
        __syncthreads();
    }

    // epilogue: lane holds C[wm*64+mi*16+4g+r][wn*64+ni*16+q]
    #pragma unroll
    for (int ni = 0; ni < 4; ++ni) {
        const int col = bn + wn * 64 + ni * 16 + q;
        const float bv = bias[col];
        #pragma unroll
        for (int mi = 0; mi < 4; ++mi) {
            const int rl0 = blocal + wm * 64 + mi * 16 + 4 * g;  // row within batch
            #pragma unroll
            for (int r = 0; r < 4; ++r) {
                const int rl = rl0 + r;
                const float v = acc[mi][ni][r] + bv;
                if (mode == 2) {
                    outF[(size_t)(bm + wm * 64 + mi * 16 + 4 * g + r) * 1024 + col] = v;
                } else if (mode == 1) {
                    const int h = col >> 6, d = col & 63;
                    outQ[(((size_t)(bb * HC + h)) * SC + rowOff + rl) * DC + d] =
                        f2bf(v * QSCALE);
                } else {
                    const int which = col >> 10;
                    const int hd = col & 1023;
                    const int h = hd >> 6, d = hd & 63;
                    const size_t bh = (size_t)(bb * HC + h);
                    if (which == 0)
                        outQ[(bh * SC + rl) * DC + d] = f2bf(v * QSCALE);
                    else if (which == 1)
                        outK[(bh * ANC + rl) * DC + d] = f2bf(v);
                    else
                        outVt[(bh * DC + d) * ANC + rl] = f2bf(v);  // transposed V
                }
            }
        }
    }
}

// ---------------- persistent-KV bf16 MFMA attention ----------------
// Grid 256 = 4 blocks per (b,h). Block stages K (64KB) + V^T (64KB) into
// 128KB LDS ONCE (1 barrier), then 8 waves independently sweep 8 query-tiles
// of 16 rows each (no barriers in the loop; LDS is read-only).
// Swizzle: byte ^= (row&7)<<4 on both store and read -> 2-way max (free).
// Swapped QK^T (mfma(K,Q)): lane(q,g) holds S^T[16t+4g+r][q]; split k-map
// cancels between the two operands of each mfma (verified in rounds 2-3).
// NOTE: exp MUST be a builtin (exp2f), NOT inline asm — v_exp_f32 is a
// TRANS op with a result-latency hazard the compiler can't see inside asm.
__global__ __launch_bounds__(512) void attn_mfma(
    const short* __restrict__ Qb,   // (BH, S, D) bf16, pre-scaled by log2e/8
    const short* __restrict__ Kb,   // (BH, A, D) bf16
    const short* __restrict__ Vtb,  // (BH, D, A) bf16
    short* __restrict__ Aout)       // (B, S, DIM) bf16
{
    __shared__ __align__(16) char lds[131072];   // K at 0, V^T at 65536

    const int tid = threadIdx.x;
    const int wave = tid >> 6, lane = tid & 63;
    const int q = lane & 15, g = lane >> 4;
    const int bh = blockIdx.x >> 2;
    const int qc = blockIdx.x & 3;
    const int sbase = qc * 1024 + wave * 128;    // this wave's 128 queries

    // ---- stage K: rows a (128B), 16B-chunk c' = c ^ (row&7) ----
    {
        const float4* src = (const float4*)(Kb + (size_t)bh * ANC * DC);
        #pragma unroll
        for (int l = 0; l < 8; ++l) {
            int i = l * 512 + tid;
            int row = i >> 3, c = i & 7;
            *(float4*)(lds + row * 128 + ((c ^ (row & 7)) << 4)) = src[i];
        }
    }
    // ---- stage V^T: rows d (1024B), 16B-chunk c' = c ^ (row&7) ----
    {
        const float4* src = (const float4*)(Vtb + (size_t)bh * DC * ANC);
        #pragma unroll
        for (int l = 0; l < 8; ++l) {
            int i = l * 512 + tid;
            int row = i >> 6, c = i & 63;
            *(float4*)(lds + 65536 + row * 1024 + ((c ^ (row & 7)) << 4)) = src[i];
        }
    }
    __syncthreads();

    const int sw = (q & 7) << 4;     // row&7 == q&7 for rows 16t+q
    const size_t qrow0 = (size_t)bh * SC;

    // prologue: Q fragments for tile 0
    s16x8 qf[2];
    {
        const short* Qp = Qb + (qrow0 + sbase + q) * DC;
        #pragma unroll
        for (int kk = 0; kk < 2; ++kk) {
            s16x4 lo = *(const s16x4*)(Qp + 32 * kk + 4 * g);
            s16x4 hi = *(const s16x4*)(Qp + 32 * kk + 16 + 4 * g);
            qf[kk] = (s16x8){lo[0], lo[1], lo[2], lo[3], hi[0], hi[1], hi[2], hi[3]};
        }
    }

    for (int t8 = 0; t8 < 8; ++t8) {
        const int s0 = sbase + t8 * 16;

        // ---- QK^T: 32 tiles x f32x4 ----
        f32x4 sacc[32];
        #pragma unroll
        for (int t = 0; t < 32; ++t) sacc[t] = (f32x4){0.f, 0.f, 0.f, 0.f};
        #pragma unroll
        for (int t = 0; t < 32; ++t) {
            const char* krow = lds + (16 * t + q) * 128;
            #pragma unroll
            for (int kk = 0; kk < 2; ++kk) {
                s16x4 lo = *(const s16x4*)(krow + ((64 * kk + 8 * g) ^ sw));
                s16x4 hi = *(const s16x4*)(krow + ((64 * kk + 32 + 8 * g) ^ sw));
                s16x8 kf = (s16x8){lo[0], lo[1], lo[2], lo[3], hi[0], hi[1], hi[2], hi[3]};
                sacc[t] = __builtin_amdgcn_mfma_f32_16x16x32_bf16(kf, qf[kk], sacc[t], 0, 0, 0);
            }
        }

        // ---- prefetch next tile's Q fragments (clamped in-bounds at last tile) ----
        s16x8 qn[2];
        {
            const int snext = (t8 < 7) ? (s0 + 16) : sbase;
            const short* Qp = Qb + (qrow0 + snext + q) * DC;
            #pragma unroll
            for (int kk = 0; kk < 2; ++kk) {
                s16x4 lo = *(const s16x4*)(Qp + 32 * kk + 4 * g);
                s16x4 hi = *(const s16x4*)(Qp + 32 * kk + 16 + 4 * g);
                qn[kk] = (s16x8){lo[0], lo[1], lo[2], lo[3], hi[0], hi[1], hi[2], hi[3]};
            }
        }

        // ---- softmax: e = 2^score (Q pre-scaled by log2e/8), 4 partial sums ----
        float ps0 = 0.f, ps1 = 0.f, ps2 = 0.f, ps3 = 0.f;
        #pragma unroll
        for (int t = 0; t < 32; ++t) {
            float e0 = exp2f(sacc[t][0]), e1 = exp2f(sacc[t][1]);
            float e2 = exp2f(sacc[t][2]), e3 = exp2f(sacc[t][3]);
            sacc[t][0] = e0; sacc[t][1] = e1; sacc[t][2] = e2; sacc[t][3] = e3;
            ps0 += e0; ps1 += e1; ps2 += e2; ps3 += e3;
        }
        float sum = (ps0 + ps1) + (ps2 + ps3);
        sum += __shfl_xor(sum, 16);
        sum += __shfl_xor(sum, 32);
        const float rinv = 1.0f / sum;

        // ---- pack P to bf16 fragments via v_cvt_pk_bf16_f32 (VOP3, hazard-safe) ----
        s16x8 pf[16];
        #pragma unroll
        for (int t2 = 0; t2 < 16; ++t2) {
            union { s16x8 v; unsigned u[4]; } pk;
            pk.u[0] = cvtpk(sacc[2 * t2][0],     sacc[2 * t2][1]);
            pk.u[1] = cvtpk(sacc[2 * t2][2],     sacc[2 * t2][3]);
            pk.u[2] = cvtpk(sacc[2 * t2 + 1][0], sacc[2 * t2 + 1][1]);
            pk.u[3] = cvtpk(sacc[2 * t2 + 1][2], sacc[2 * t2 + 1][3]);
            pf[t2] = pk.v;
        }

        // ---- PV: O^T (64 d x 16 q) ----
        f32x4 oacc[4];
        #pragma unroll
        for (int md = 0; md < 4; ++md) oacc[md] = (f32x4){0.f, 0.f, 0.f, 0.f};
        #pragma unroll
        for (int t2 = 0; t2 < 16; ++t2) {
            #pragma unroll
            for (int md = 0; md < 4; ++md) {
                const char* vrow = lds + 65536 + (16 * md + q) * 1024;
                s16x4 lo = *(const s16x4*)(vrow + ((64 * t2 + 8 * g) ^ sw));
                s16x4 hi = *(const s16x4*)(vrow + ((64 * t2 + 32 + 8 * g) ^ sw));
                s16x8 vf = (s16x8){lo[0], lo[1], lo[2], lo[3], hi[0], hi[1], hi[2], hi[3]};
                oacc[md] = __builtin_amdgcn_mfma_f32_16x16x32_bf16(vf, pf[t2], oacc[md], 0, 0, 0);
            }
        }

        // ---- store: lane holds O[q][16md+4g+r]; packed 8B bf16 stores ----
        short* op = Aout + ((size_t)(bh >> 4) * SC + s0 + q) * DIMC + (bh & 15) * DC;
        #pragma unroll
        for (int md = 0; md < 4; ++md) {
            union { s16x4 v; unsigned u[2]; } ow;
            ow.u[0] = cvtpk(oacc[md][0] * rinv, oacc[md][1] * rinv);
            ow.u[1] = cvtpk(oacc[md][2] * rinv, oacc[md][3] * rinv);
            *(s16x4*)(op + 16 * md + 4 * g) = ow.v;
        }

        qf[0] = qn[0];
        qf[1] = qn[1];
    }
}

// ---------------- launcher ----------------
extern "C" void kernel_launch(void* const* d_in, const int* in_sizes, int n_in,
                              void* d_out, int out_size, void* d_ws, size_t ws_size,
                              hipStream_t stream)
{
    (void)in_sizes; (void)n_in; (void)out_size; (void)ws_size;

    const float* x     = (const float*)d_in[0];
    const float* Wqkv  = (const float*)d_in[1];
    const float* bqkv  = (const float*)d_in[2];
    const float* Wq    = (const float*)d_in[3];
    const float* bq    = (const float*)d_in[4];
    const float* Wproj = (const float*)d_in[5];
    const float* bproj = (const float*)d_in[6];

    // d_out (67 MB fp32) doubles as scratch before the final GEMM overwrites it:
    //   [xb bf16 33.5MB | Qb bf16 33.5MB]  (both dead before K4 writes d_out)
    short* xb = (short*)d_out;
    short* Qb = xb + (size_t)16777216;
    // d_ws: Kb 4.2 + Vtb 4.2 + Ab 33.5 + Wqkv_t 6.3 + Wq_t 2 + Wproj_t 2 = 50 MB
    short* Kb     = (short*)d_ws;
    short* Vtb    = Kb  + (size_t)2097152;
    short* Ab     = Vtb + (size_t)2097152;
    short* Wqkvt  = Ab  + (size_t)16777216;
    short* Wqt    = Wqkvt + (size_t)3145728;
    short* Wprojt = Wqt   + (size_t)1048576;

    // pre-passes
    cast_f32_bf16<<<dim3(2048), dim3(256), 0, stream>>>(x, xb, 16777216 / 4);
    transpose_cast<<<dim3(96, 32), dim3(256), 0, stream>>>(Wqkv, Wqkvt, 1024, 3072);
    transpose_cast<<<dim3(32, 32), dim3(256), 0, stream>>>(Wq, Wqt, 1024, 1024);
    transpose_cast<<<dim3(32, 32), dim3(256), 0, stream>>>(Wproj, Wprojt, 1024, 1024);

    // K1: anchors @ Wqkv + bqkv -> Qb(s<512), Kb, Vtb
    gemm_bf16<<<dim3(24, 16), dim3(256), 0, stream>>>(
        xb, Wqkvt, bqkv, nullptr, Qb, Kb, Vtb, ANC, 0, 0);

    // K2: queries @ Wq + bq -> Qb(s>=512)
    gemm_bf16<<<dim3(8, 112), dim3(256), 0, stream>>>(
        xb, Wqt, bq, nullptr, Qb, nullptr, nullptr, QNC, ANC, 1);

    // K3: persistent-KV MFMA attention -> Ab (bf16)
    attn_mfma<<<dim3(256), dim3(512), 0, stream>>>(Qb, Kb, Vtb, Ab);

    // K4: Ab @ Wproj + bproj -> d_out (fp32)
    gemm_bf16<<<dim3(8, 128), dim3(256), 0, stream>>>(
        Ab, Wprojt, bproj, (float*)d_out, nullptr, nullptr, nullptr, 16384, 0, 2);
}

// Round 6
// 267.033 us; speedup vs baseline: 1.4295x; 1.4295x over previous
//
#include <hip/hip_runtime.h>
#include <hip/hip_bf16.h>

// Problem constants (fixed by setup_inputs)
#define DIMC 1024
#define HC   16
#define DC   64
#define BC   4
#define SC   4096
#define ANC  512          // num_anchor_tokens
#define QNC  3584         // S - A
#define GK   1024         // K-dim of every GEMM (= DIMC)
// Q pre-scale: 1/sqrt(64) * log2(e)  (softmax exp done as exp2f; any Q scale
// just moves where bf16 rounding happens — relative error unchanged)
#define QSCALE (0.125f * 1.44269504088896f)

typedef __attribute__((ext_vector_type(4))) float f32x4;
typedef __attribute__((ext_vector_type(8))) short s16x8;
typedef __attribute__((ext_vector_type(4))) short s16x4;

__device__ inline short f2bf(float f) {
    unsigned u = __builtin_bit_cast(unsigned, f);
    u += 0x7fff + ((u >> 16) & 1);          // RNE
    return (short)(u >> 16);
}
__device__ inline unsigned cvtpk(float lo, float hi) {   // dst = {lo16: bf(lo), hi16: bf(hi)}
    unsigned d;
    asm("v_cvt_pk_bf16_f32 %0, %1, %2" : "=v"(d) : "v"(lo), "v"(hi));
    return d;
}

// async 16B global -> LDS (linear dest: wave-uniform base + lane*16)
#define GLOAD16(gp, lp) __builtin_amdgcn_global_load_lds( \
    (const __attribute__((address_space(1))) void*)(gp),  \
    (__attribute__((address_space(3))) void*)(lp), 16, 0, 0)

// ---------------- pre-pass: cast x to bf16 ----------------
__global__ __launch_bounds__(256) void cast_f32_bf16(
    const float* __restrict__ in, short* __restrict__ out, int n4)
{
    int i = blockIdx.x * blockDim.x + threadIdx.x;
    const int stride = gridDim.x * blockDim.x;
    for (; i < n4; i += stride) {
        float4 v = ((const float4*)in)[i];
        s16x4 o = { f2bf(v.x), f2bf(v.y), f2bf(v.z), f2bf(v.w) };
        ((s16x4*)out)[i] = o;
    }
}

// ---------------- pre-pass: W (K x N fp32) -> Wt (N x K bf16) ----------------
__global__ __launch_bounds__(256) void transpose_cast(
    const float* __restrict__ W, short* __restrict__ Wt, int K, int N)
{
    __shared__ float t[32][33];
    const int tx = threadIdx.x & 31, ty = threadIdx.x >> 5;  // 32 x 8
    const int nt = blockIdx.x * 32, kt = blockIdx.y * 32;
    #pragma unroll
    for (int j = 0; j < 4; ++j)
        t[ty + 8 * j][tx] = W[(size_t)(kt + ty + 8 * j) * N + nt + tx];
    __syncthreads();
    #pragma unroll
    for (int j = 0; j < 4; ++j)
        Wt[(size_t)(nt + ty + 8 * j) * K + kt + tx] = f2bf(t[tx][ty + 8 * j]);
}

// ---------------- bf16 MFMA GEMM (m97 structure: 128x128 tile, BK=32) ----------------
// mode: 0 = qkv scatter (bf16 Q/K/Vt), 1 = q scatter (bf16 Q), 2 = fp32 plain.
__global__ __launch_bounds__(256) void gemm_bf16(
    const short* __restrict__ Abase, const short* __restrict__ Bt,
    const float* __restrict__ bias,
    float* __restrict__ outF, short* __restrict__ outQ,
    short* __restrict__ outK, short* __restrict__ outVt,
    int rowsPerB, int rowOff, int mode)
{
    __shared__ __align__(16) short Als[128 * 32];   // [row][k] linear, 8 KB
    __shared__ __align__(16) short Bls[128 * 32];   // [n][k]  linear, 8 KB

    const int tid = threadIdx.x;
    const int wave = tid >> 6, lane = tid & 63;
    const int q = lane & 15, g = lane >> 4;
    const int wm = wave >> 1, wn = wave & 1;

    const int bm = blockIdx.y * 128, bn = blockIdx.x * 128;
    const int bb = bm / rowsPerB;            // batch index (tiles never straddle)
    const int blocal = bm % rowsPerB;
    const char* Arow0 = (const char*)(Abase + ((size_t)bb * SC + rowOff + blocal) * GK);
    const char* Brow0 = (const char*)(Bt + (size_t)bn * GK);

    const int ca0 = wave * 64 + lane;        // 0..255   (rows 0..63)
    const int ca1 = (4 + wave) * 64 + lane;  // 256..511 (rows 64..127)
    const int a0r = (ca0 >> 2) * (GK * 2), a0c = (ca0 & 3) * 16;
    const int a1r = (ca1 >> 2) * (GK * 2), a1c = (ca1 & 3) * 16;

    f32x4 acc[4][4];
    #pragma unroll
    for (int i = 0; i < 4; ++i)
        #pragma unroll
        for (int j = 0; j < 4; ++j) acc[i][j] = (f32x4){0.f, 0.f, 0.f, 0.f};

    for (int k0 = 0; k0 < GK; k0 += 32) {
        const int kb = k0 * 2;               // byte offset within a row
        GLOAD16(Arow0 + a0r + kb + a0c, (char*)Als + ca0 * 16);
        GLOAD16(Arow0 + a1r + kb + a1c, (char*)Als + ca1 * 16);
        GLOAD16(Brow0 + a0r + kb + a0c, (char*)Bls + ca0 * 16);
        GLOAD16(Brow0 + a1r + kb + a1c, (char*)Bls + ca1 * 16);
        __syncthreads();

        s16x8 aF[4], bF[4];
        #pragma unroll
        for (int mi = 0; mi < 4; ++mi)
            aF[mi] = *(const s16x8*)((const char*)Als + (wm * 64 + mi * 16 + q) * 64 + g * 16);
        #pragma unroll
        for (int ni = 0; ni < 4; ++ni)
            bF[ni] = *(const s16x8*)((const char*)Bls + (wn * 64 + ni * 16 + q) * 64 + g * 16);
        #pragma unroll
        for (int mi = 0; mi < 4; ++mi)
            #pragma unroll
            for (int ni = 0; ni < 4; ++ni)
                acc[mi][ni] = __builtin_amdgcn_mfma_f32_16x16x32_bf16(
                    aF[mi], bF[ni], acc[mi][ni], 0, 0, 0);
        __syncthreads();
    }

    // epilogue: lane holds C[wm*64+mi*16+4g+r][wn*64+ni*16+q]
    #pragma unroll
    for (int ni = 0; ni < 4; ++ni) {
        const int col = bn + wn * 64 + ni * 16 + q;
        const float bv = bias[col];
        #pragma unroll
        for (int mi = 0; mi < 4; ++mi) {
            const int rl0 = blocal + wm * 64 + mi * 16 + 4 * g;  // row within batch
            #pragma unroll
            for (int r = 0; r < 4; ++r) {
                const int rl = rl0 + r;
                const float v = acc[mi][ni][r] + bv;
                if (mode == 2) {
                    outF[(size_t)(bm + wm * 64 + mi * 16 + 4 * g + r) * 1024 + col] = v;
                } else if (mode == 1) {
                    const int h = col >> 6, d = col & 63;
                    outQ[(((size_t)(bb * HC + h)) * SC + rowOff + rl) * DC + d] =
                        f2bf(v * QSCALE);
                } else {
                    const int which = col >> 10;
                    const int hd = col & 1023;
                    const int h = hd >> 6, d = hd & 63;
                    const size_t bh = (size_t)(bb * HC + h);
                    if (which == 0)
                        outQ[(bh * SC + rl) * DC + d] = f2bf(v * QSCALE);
                    else if (which == 1)
                        outK[(bh * ANC + rl) * DC + d] = f2bf(v);
                    else
                        outVt[(bh * DC + d) * ANC + rl] = f2bf(v);  // transposed V
                }
            }
        }
    }
}

// ---------------- persistent-KV bf16 MFMA attention ----------------
// Grid 256 = 4 blocks per (b,h). Block stages K (64KB) + V^T (64KB) ONCE,
// then 8 waves independently sweep 8 query-tiles of 16 rows (no barriers in
// the loop). Each wave has a private 2KB LDS slot used to (a) stage Q tiles
// with fully-coalesced 32B/lane loads, and (b) bounce O so global stores are
// lane-contiguous 16B chunks (sector-complete 128B rows).
// Swizzle everywhere: 16B-chunk index ^= (row&7) -> <=2-way conflicts (free).
// Swapped QK^T (mfma(K,Q)): lane(q,g) holds S^T[16t+4g+r][q]; split k-map
// cancels between the two operands of each mfma (verified rounds 2/3/5).
// exp MUST be builtin exp2f, NOT inline asm (TRANS hazard — round-4 failure).
__global__ __launch_bounds__(512) void attn_mfma(
    const short* __restrict__ Qb,   // (BH, S, D) bf16, pre-scaled by log2e/8
    const short* __restrict__ Kb,   // (BH, A, D) bf16
    const short* __restrict__ Vtb,  // (BH, D, A) bf16
    short* __restrict__ Aout)       // (B, S, DIM) bf16
{
    __shared__ __align__(16) char lds[147456];   // K | V^T | 8 x 2KB wave slots

    const int tid = threadIdx.x;
    const int wave = tid >> 6, lane = tid & 63;
    const int q = lane & 15, g = lane >> 4;
    const int bh = blockIdx.x >> 2;
    const int qc = blockIdx.x & 3;
    const int sbase = qc * 1024 + wave * 128;    // this wave's 128 queries

    // ---- stage K: rows a (128B), 16B-chunk c' = c ^ (row&7) ----
    {
        const float4* src = (const float4*)(Kb + (size_t)bh * ANC * DC);
        #pragma unroll
        for (int l = 0; l < 8; ++l) {
            int i = l * 512 + tid;
            int row = i >> 3, c = i & 7;
            *(float4*)(lds + row * 128 + ((c ^ (row & 7)) << 4)) = src[i];
        }
    }
    // ---- stage V^T: rows d (1024B), 16B-chunk c' = c ^ (row&7) ----
    {
        const float4* src = (const float4*)(Vtb + (size_t)bh * DC * ANC);
        #pragma unroll
        for (int l = 0; l < 8; ++l) {
            int i = l * 512 + tid;
            int row = i >> 6, c = i & 63;
            *(float4*)(lds + 65536 + row * 1024 + ((c ^ (row & 7)) << 4)) = src[i];
        }
    }
    __syncthreads();

    char* slot = lds + 131072 + wave * 2048;
    const int sw = (q & 7) << 4;          // row&7 == q&7 for rows 16t+q
    const int srow = lane >> 2, sc2 = lane & 3;   // staging: row 0..15, 32B chunk
    const int wb0 = srow * 128 + (((sc2 * 2 + 0) ^ (srow & 7)) << 4);
    const int wb1 = srow * 128 + (((sc2 * 2 + 1) ^ (srow & 7)) << 4);
    const size_t qrow0 = (size_t)bh * SC;

    // prologue: coalesced load of tile 0's Q (2KB per wave: 32B per lane)
    float4 gl0, gl1;
    {
        const char* Qsrc = (const char*)(Qb + (qrow0 + sbase) * DC);
        gl0 = *(const float4*)(Qsrc + lane * 32);
        gl1 = *(const float4*)(Qsrc + lane * 32 + 16);
    }

    for (int t8 = 0; t8 < 8; ++t8) {
        const int s0 = sbase + t8 * 16;

        // ---- write staged Q into this wave's slot (swizzled) ----
        *(float4*)(slot + wb0) = gl0;
        *(float4*)(slot + wb1) = gl1;
        __asm__ __volatile__("" ::: "memory");   // keep LDS write->read order

        // ---- Q fragments from slot (same algebra as K reads) ----
        s16x8 qf[2];
        #pragma unroll
        for (int kk = 0; kk < 2; ++kk) {
            s16x4 lo = *(const s16x4*)(slot + q * 128 + ((64 * kk + 8 * g) ^ sw));
            s16x4 hi = *(const s16x4*)(slot + q * 128 + ((64 * kk + 32 + 8 * g) ^ sw));
            qf[kk] = (s16x8){lo[0], lo[1], lo[2], lo[3], hi[0], hi[1], hi[2], hi[3]};
        }

        // ---- QK^T: 32 tiles x f32x4 ----
        f32x4 sacc[32];
        #pragma unroll
        for (int t = 0; t < 32; ++t) sacc[t] = (f32x4){0.f, 0.f, 0.f, 0.f};
        #pragma unroll
        for (int t = 0; t < 32; ++t) {
            const char* krow = lds + (16 * t + q) * 128;
            #pragma unroll
            for (int kk = 0; kk < 2; ++kk) {
                s16x4 lo = *(const s16x4*)(krow + ((64 * kk + 8 * g) ^ sw));
                s16x4 hi = *(const s16x4*)(krow + ((64 * kk + 32 + 8 * g) ^ sw));
                s16x8 kf = (s16x8){lo[0], lo[1], lo[2], lo[3], hi[0], hi[1], hi[2], hi[3]};
                sacc[t] = __builtin_amdgcn_mfma_f32_16x16x32_bf16(kf, qf[kk], sacc[t], 0, 0, 0);
            }
        }

        // ---- prefetch next tile's Q chunk (coalesced; clamped at last tile) ----
        {
            const int snext = (t8 < 7) ? (s0 + 16) : sbase;
            const char* Qsrc = (const char*)(Qb + (qrow0 + snext) * DC);
            gl0 = *(const float4*)(Qsrc + lane * 32);
            gl1 = *(const float4*)(Qsrc + lane * 32 + 16);
            // pin the loads here so they can't sink to next-iteration use
            __asm__ __volatile__("" : "+v"(gl0.x), "+v"(gl0.y), "+v"(gl0.z),
                                      "+v"(gl0.w), "+v"(gl1.x), "+v"(gl1.y),
                                      "+v"(gl1.z), "+v"(gl1.w));
        }

        // ---- softmax: e = 2^score (Q pre-scaled by log2e/8), 4 partial sums ----
        float ps0 = 0.f, ps1 = 0.f, ps2 = 0.f, ps3 = 0.f;
        #pragma unroll
        for (int t = 0; t < 32; ++t) {
            float e0 = exp2f(sacc[t][0]), e1 = exp2f(sacc[t][1]);
            float e2 = exp2f(sacc[t][2]), e3 = exp2f(sacc[t][3]);
            sacc[t][0] = e0; sacc[t][1] = e1; sacc[t][2] = e2; sacc[t][3] = e3;
            ps0 += e0; ps1 += e1; ps2 += e2; ps3 += e3;
        }
        float sum = (ps0 + ps1) + (ps2 + ps3);
        sum += __shfl_xor(sum, 16);
        sum += __shfl_xor(sum, 32);
        const float rinv = 1.0f / sum;

        // ---- pack P to bf16 fragments via v_cvt_pk_bf16_f32 (VOP3, hazard-safe) ----
        s16x8 pf[16];
        #pragma unroll
        for (int t2 = 0; t2 < 16; ++t2) {
            union { s16x8 v; unsigned u[4]; } pk;
            pk.u[0] = cvtpk(sacc[2 * t2][0],     sacc[2 * t2][1]);
            pk.u[1] = cvtpk(sacc[2 * t2][2],     sacc[2 * t2][3]);
            pk.u[2] = cvtpk(sacc[2 * t2 + 1][0], sacc[2 * t2 + 1][1]);
            pk.u[3] = cvtpk(sacc[2 * t2 + 1][2], sacc[2 * t2 + 1][3]);
            pf[t2] = pk.v;
        }

        // ---- PV: O^T (64 d x 16 q) ----
        f32x4 oacc[4];
        #pragma unroll
        for (int md = 0; md < 4; ++md) oacc[md] = (f32x4){0.f, 0.f, 0.f, 0.f};
        #pragma unroll
        for (int t2 = 0; t2 < 16; ++t2) {
            #pragma unroll
            for (int md = 0; md < 4; ++md) {
                const char* vrow = lds + 65536 + (16 * md + q) * 1024;
                s16x4 lo = *(const s16x4*)(vrow + ((64 * t2 + 8 * g) ^ sw));
                s16x4 hi = *(const s16x4*)(vrow + ((64 * t2 + 32 + 8 * g) ^ sw));
                s16x8 vf = (s16x8){lo[0], lo[1], lo[2], lo[3], hi[0], hi[1], hi[2], hi[3]};
                oacc[md] = __builtin_amdgcn_mfma_f32_16x16x32_bf16(vf, pf[t2], oacc[md], 0, 0, 0);
            }
        }

        // ---- bounce O through slot, then lane-contiguous 16B global stores ----
        __asm__ __volatile__("" ::: "memory");
        #pragma unroll
        for (int md = 0; md < 4; ++md) {
            union { unsigned long long d; unsigned u[2]; } ow;
            ow.u[0] = cvtpk(oacc[md][0] * rinv, oacc[md][1] * rinv);
            ow.u[1] = cvtpk(oacc[md][2] * rinv, oacc[md][3] * rinv);
            *(unsigned long long*)(slot + q * 128 + ((32 * md + 8 * g) ^ sw)) = ow.d;
        }
        __asm__ __volatile__("" ::: "memory");
        {
            float4 o0 = *(const float4*)(slot + wb0);
            float4 o1 = *(const float4*)(slot + wb1);
            char* Op = (char*)Aout +
                (((size_t)(bh >> 4) * SC + s0 + srow) * DIMC + (bh & 15) * DC) * 2 +
                sc2 * 32;
            *(float4*)(Op) = o0;
            *(float4*)(Op + 16) = o1;
        }
    }
}

// ---------------- launcher ----------------
extern "C" void kernel_launch(void* const* d_in, const int* in_sizes, int n_in,
                              void* d_out, int out_size, void* d_ws, size_t ws_size,
                              hipStream_t stream)
{
    (void)in_sizes; (void)n_in; (void)out_size; (void)ws_size;

    const float* x     = (const float*)d_in[0];
    const float* Wqkv  = (const float*)d_in[1];
    const float* bqkv  = (const float*)d_in[2];
    const float* Wq    = (const float*)d_in[3];
    const float* bq    = (const float*)d_in[4];
    const float* Wproj = (const float*)d_in[5];
    const float* bproj = (const float*)d_in[6];

    // d_out (67 MB fp32) doubles as scratch before the final GEMM overwrites it:
    //   [xb bf16 33.5MB | Qb bf16 33.5MB]  (both dead before K4 writes d_out)
    short* xb = (short*)d_out;
    short* Qb = xb + (size_t)16777216;
    // d_ws: Kb 4.2 + Vtb 4.2 + Ab 33.5 + Wqkv_t 6.3 + Wq_t 2 + Wproj_t 2 = 50 MB
    short* Kb     = (short*)d_ws;
    short* Vtb    = Kb  + (size_t)2097152;
    short* Ab     = Vtb + (size_t)2097152;
    short* Wqkvt  = Ab  + (size_t)16777216;
    short* Wqt    = Wqkvt + (size_t)3145728;
    short* Wprojt = Wqt   + (size_t)1048576;

    // pre-passes
    cast_f32_bf16<<<dim3(2048), dim3(256), 0, stream>>>(x, xb, 16777216 / 4);
    transpose_cast<<<dim3(96, 32), dim3(256), 0, stream>>>(Wqkv, Wqkvt, 1024, 3072);
    transpose_cast<<<dim3(32, 32), dim3(256), 0, stream>>>(Wq, Wqt, 1024, 1024);
    transpose_cast<<<dim3(32, 32), dim3(256), 0, stream>>>(Wproj, Wprojt, 1024, 1024);

    // K1: anchors @ Wqkv + bqkv -> Qb(s<512), Kb, Vtb
    gemm_bf16<<<dim3(24, 16), dim3(256), 0, stream>>>(
        xb, Wqkvt, bqkv, nullptr, Qb, Kb, Vtb, ANC, 0, 0);

    // K2: queries @ Wq + bq -> Qb(s>=512)
    gemm_bf16<<<dim3(8, 112), dim3(256), 0, stream>>>(
        xb, Wqt, bq, nullptr, Qb, nullptr, nullptr, QNC, ANC, 1);

    // K3: persistent-KV MFMA attention -> Ab (bf16)
    attn_mfma<<<dim3(256), dim3(512), 0, stream>>>(Qb, Kb, Vtb, Ab);

    // K4: Ab @ Wproj + bproj -> d_out (fp32)
    gemm_bf16<<<dim3(8, 128), dim3(256), 0, stream>>>(
        Ab, Wprojt, bproj, (float*)d_out, nullptr, nullptr, nullptr, 16384, 0, 2);
}